// Round 1
// baseline (542.430 us; speedup 1.0000x reference)
//
#include <hip/hip_runtime.h>

typedef __attribute__((ext_vector_type(4))) float f32x4;
typedef __attribute__((ext_vector_type(8))) short s16x8;
typedef unsigned short u16;

#define NV 8192
#define NE 16384
#define MTOT 24576
#define DD 128
#define HH 256

// ---------- helpers ----------
__device__ __forceinline__ u16 f2bf(float f) {
    unsigned u = __builtin_bit_cast(unsigned, f);
    u += 0x7fffu + ((u >> 16) & 1u);   // RTNE
    return (u16)(u >> 16);
}

__device__ __forceinline__ float wsum(float v) {
#pragma unroll
    for (int o = 32; o > 0; o >>= 1) v += __shfl_xor(v, o, 64);
    return v;
}

// ---------- PE tables ----------
__global__ void k_pe(float* __restrict__ pe1, float* __restrict__ pe2) {
    const float c = logf(10000.0f) / 64.0f;
    for (int idx = threadIdx.x; idx < 9 * DD; idx += 256) {
        int p = idx / DD, col = idx % DD, j = col >> 1;
        float a = (float)p * expf(-(float)j * c);
        pe1[idx] = (col & 1) ? cosf(a) : sinf(a);
    }
    for (int idx = threadIdx.x; idx < 2 * DD; idx += 256) {
        int p = idx / DD, col = idx % DD, j = col >> 1;
        float a = (float)p * expf(-(float)j * c);
        pe2[idx] = (col & 1) ? cosf(a) : sinf(a);
    }
}

// ---------- transpose+convert weights: src fp32 [R][C] -> dst bf16 [C][R] ----------
__global__ void k_twcvt(const float* __restrict__ src, u16* __restrict__ dst, int R, int C) {
    int i = blockIdx.x * 256 + threadIdx.x;
    if (i < R * C) {
        int r = i / C, c = i % C;
        dst[(size_t)c * R + r] = f2bf(src[i]);
    }
}

// ---------- LN + concat(PE) for stage 1: rows 0..NV-1 from x_v (pe1 row1), NV.. from x_e (pe1[orders]) ----------
__global__ __launch_bounds__(256) void k_ln_cat1(const float* __restrict__ xv, const float* __restrict__ xe,
                                                 const int* __restrict__ orders, const float* __restrict__ pe1,
                                                 const float* __restrict__ g, const float* __restrict__ bn,
                                                 u16* __restrict__ cat) {
    int wave = threadIdx.x >> 6, lane = threadIdx.x & 63;
    int row = blockIdx.x * 4 + wave;
    const float* x = (row < NV) ? xv + (size_t)row * DD : xe + (size_t)(row - NV) * DD;
    float2 v = *(const float2*)(x + lane * 2);
    float mu = wsum(v.x + v.y) * (1.0f / DD);
    float var = wsum(v.x * v.x + v.y * v.y) * (1.0f / DD) - mu * mu;
    float rs = rsqrtf(var + 1e-5f);
    int c = lane * 2;
    u16* crow = cat + (size_t)row * 256;
    crow[c]     = f2bf((v.x - mu) * rs * g[c]     + bn[c]);
    crow[c + 1] = f2bf((v.y - mu) * rs * g[c + 1] + bn[c + 1]);
    const float* pr = pe1 + (size_t)((row < NV) ? 1 : orders[row - NV]) * DD;
    crow[DD + c]     = f2bf(pr[c]);
    crow[DD + c + 1] = f2bf(pr[c + 1]);
}

// ---------- MFMA core: 4 waves, each owns 16 rows, N<=256, K<=256 ----------
template <int K, int NN>
__device__ __forceinline__ void fc_core(const u16* __restrict__ A, const u16* __restrict__ Bt,
                                        int rowb, int lane, f32x4* acc) {
    const int kb = (lane >> 4) * 8;
    const u16* ap = A + (size_t)(rowb + (lane & 15)) * K + kb;
    const u16* bp = Bt + (size_t)(lane & 15) * K + kb;
#pragma unroll
    for (int ks = 0; ks < K / 32; ++ks) {
        s16x8 a = *(const s16x8*)(ap + ks * 32);
#pragma unroll
        for (int nt = 0; nt < NN / 16; ++nt) {
            s16x8 b = *(const s16x8*)(bp + (size_t)nt * 16 * K + ks * 32);
            acc[nt] = __builtin_amdgcn_mfma_f32_16x16x32_bf16(a, b, acc[nt], 0, 0, 0);
        }
    }
}

// ---------- fc1: out = relu(A@W + b), out bf16 [M][NN] ----------
template <int K, int NN>
__global__ __launch_bounds__(256) void k_fc_relu(const u16* __restrict__ A, const u16* __restrict__ Bt,
                                                 const float* __restrict__ bias, u16* __restrict__ out) {
    int lane = threadIdx.x & 63, wave = threadIdx.x >> 6;
    int rowb = blockIdx.x * 64 + wave * 16;
    f32x4 acc[NN / 16];
#pragma unroll
    for (int nt = 0; nt < NN / 16; ++nt)
#pragma unroll
        for (int j = 0; j < 4; ++j) acc[nt][j] = 0.0f;
    fc_core<K, NN>(A, Bt, rowb, lane, acc);
#pragma unroll
    for (int nt = 0; nt < NN / 16; ++nt)
#pragma unroll
        for (int j = 0; j < 4; ++j) {
            int r = rowb + ((lane >> 4) << 2) + j;
            int c = nt * 16 + (lane & 15);
            float v = acc[nt][j] + bias[c];
            out[(size_t)r * NN + c] = f2bf(fmaxf(v, 0.0f));
        }
}

// ---------- fc2 stage1: xnew = residual(x_v/x_e) + A@W + b; also x_eT bf16 ----------
__global__ __launch_bounds__(256) void k_fc2_s1(const u16* __restrict__ A, const u16* __restrict__ Bt,
                                                const float* __restrict__ bias, const float* __restrict__ xv,
                                                const float* __restrict__ xe, float* __restrict__ xnew,
                                                u16* __restrict__ xeT) {
    int lane = threadIdx.x & 63, wave = threadIdx.x >> 6;
    int rowb = blockIdx.x * 64 + wave * 16;
    f32x4 acc[8];
#pragma unroll
    for (int nt = 0; nt < 8; ++nt)
#pragma unroll
        for (int j = 0; j < 4; ++j) acc[nt][j] = 0.0f;
    fc_core<256, 128>(A, Bt, rowb, lane, acc);
#pragma unroll
    for (int nt = 0; nt < 8; ++nt)
#pragma unroll
        for (int j = 0; j < 4; ++j) {
            int r = rowb + ((lane >> 4) << 2) + j;
            int c = nt * 16 + (lane & 15);
            float res = (r < NV) ? xv[(size_t)r * DD + c] : xe[(size_t)(r - NV) * DD + c];
            float v = acc[nt][j] + bias[c] + res;
            xnew[(size_t)r * DD + c] = v;
            if (r >= NV) xeT[(size_t)c * NE + (r - NV)] = f2bf(v);
        }
}

// ---------- fc2 stage2: xmid = x1 + A@W + b + x0_new ----------
__global__ __launch_bounds__(256) void k_fc2_s2(const u16* __restrict__ A, const u16* __restrict__ Bt,
                                                const float* __restrict__ bias, const float* __restrict__ x1,
                                                const float* __restrict__ x0n, float* __restrict__ xmid) {
    int lane = threadIdx.x & 63, wave = threadIdx.x >> 6;
    int rowb = blockIdx.x * 64 + wave * 16;
    f32x4 acc[8];
#pragma unroll
    for (int nt = 0; nt < 8; ++nt)
#pragma unroll
        for (int j = 0; j < 4; ++j) acc[nt][j] = 0.0f;
    fc_core<256, 128>(A, Bt, rowb, lane, acc);
#pragma unroll
    for (int nt = 0; nt < 8; ++nt)
#pragma unroll
        for (int j = 0; j < 4; ++j) {
            int r = rowb + ((lane >> 4) << 2) + j;
            int c = nt * 16 + (lane & 15);
            xmid[(size_t)r * DD + c] = acc[nt][j] + bias[c] + x1[(size_t)r * DD + c] + x0n[c];
        }
}

// ---------- fc2 stage3: out = xmid + A@W + b + bias_b ----------
__global__ __launch_bounds__(256) void k_fc2_s3(const u16* __restrict__ A, const u16* __restrict__ Bt,
                                                const float* __restrict__ bias, const float* __restrict__ xmid,
                                                const float* __restrict__ bb, float* __restrict__ out) {
    int lane = threadIdx.x & 63, wave = threadIdx.x >> 6;
    int rowb = blockIdx.x * 64 + wave * 16;
    f32x4 acc[8];
#pragma unroll
    for (int nt = 0; nt < 8; ++nt)
#pragma unroll
        for (int j = 0; j < 4; ++j) acc[nt][j] = 0.0f;
    fc_core<256, 128>(A, Bt, rowb, lane, acc);
#pragma unroll
    for (int nt = 0; nt < 8; ++nt)
#pragma unroll
        for (int j = 0; j < 4; ++j) {
            int r = rowb + ((lane >> 4) << 2) + j;
            int c = nt * 16 + (lane & 15);
            out[(size_t)r * DD + c] = acc[nt][j] + bias[c] + xmid[(size_t)r * DD + c] + bb[c];
        }
}

// ---------- big GEMM: yp[split] = incidence[:, chunk] @ x_e_new[chunk, :]  (fp32 A converted in-reg) ----------
__global__ __launch_bounds__(256) void k_big(const float* __restrict__ inc, const u16* __restrict__ xeT,
                                             float* __restrict__ yp) {
    int lane = threadIdx.x & 63, wave = threadIdx.x >> 6;
    int row = blockIdx.x * 64 + wave * 16 + (lane & 15);
    int split = blockIdx.y;
    int k0 = split * 4096 + ((lane >> 4) << 3);
    const float* ap = inc + (size_t)row * NE + k0;
    const u16* bp = xeT + (size_t)(lane & 15) * NE + k0;
    f32x4 acc[8];
#pragma unroll
    for (int nt = 0; nt < 8; ++nt)
#pragma unroll
        for (int j = 0; j < 4; ++j) acc[nt][j] = 0.0f;
    for (int s = 0; s < 128; ++s) {
        f32x4 a0 = *(const f32x4*)(ap);
        f32x4 a1 = *(const f32x4*)(ap + 4);
        ap += 32;
        s16x8 af;
#pragma unroll
        for (int i = 0; i < 4; ++i) { af[i] = (short)f2bf(a0[i]); af[i + 4] = (short)f2bf(a1[i]); }
#pragma unroll
        for (int nt = 0; nt < 8; ++nt) {
            s16x8 b = *(const s16x8*)(bp + (size_t)nt * 16 * NE);
            acc[nt] = __builtin_amdgcn_mfma_f32_16x16x32_bf16(af, b, acc[nt], 0, 0, 0);
        }
        bp += 32;
    }
    int rbase = blockIdx.x * 64 + wave * 16 + ((lane >> 4) << 2);
#pragma unroll
    for (int nt = 0; nt < 8; ++nt)
#pragma unroll
        for (int j = 0; j < 4; ++j)
            yp[((size_t)split * NV + rbase + j) * DD + nt * 16 + (lane & 15)] = acc[nt][j];
}

// ---------- column-sum partials over xnew [MTOT][128] ----------
__global__ __launch_bounds__(256) void k_colsum(const float* __restrict__ xnew, float* __restrict__ part) {
    int t = threadIdx.x, col = t & 127, half = t >> 7;
    int r0 = blockIdx.x * 128;
    float s = 0.0f;
    for (int i = half; i < 128; i += 2) s += xnew[(size_t)(r0 + i) * DD + col];
    __shared__ float sh[256];
    sh[t] = s;
    __syncthreads();
    if (t < 128) part[blockIdx.x * 128 + t] = sh[t] + sh[t + 128];
}

// ---------- x0 path (single block): mean -> LN -> MLP2 row -> x0_new ----------
__global__ __launch_bounds__(256) void k_x0(const float* __restrict__ part, const float* __restrict__ pe2,
                                            const float* __restrict__ w1, const float* __restrict__ b1,
                                            const float* __restrict__ w2, const float* __restrict__ b2,
                                            const float* __restrict__ g, const float* __restrict__ bn,
                                            float* __restrict__ x0n) {
    __shared__ float x0[128], cat0[256], h0[256], rs_[128], rq_[128];
    int t = threadIdx.x;
    if (t < 128) {
        float s = 0.0f;
        for (int p = 0; p < 192; ++p) s += part[p * 128 + t];
        x0[t] = s * (1.0f / MTOT);
        rs_[t] = x0[t];
        rq_[t] = x0[t] * x0[t];
    }
    __syncthreads();
    for (int off = 64; off > 0; off >>= 1) {
        if (t < off) { rs_[t] += rs_[t + off]; rq_[t] += rq_[t + off]; }
        __syncthreads();
    }
    float mu = rs_[0] * (1.0f / DD);
    float var = rq_[0] * (1.0f / DD) - mu * mu;
    float rstd = rsqrtf(var + 1e-5f);
    if (t < 128) {
        cat0[t] = (x0[t] - mu) * rstd * g[t] + bn[t];
        cat0[128 + t] = pe2[t];  // pe2 row 0
    }
    __syncthreads();
    {
        float s = b1[t];
        for (int i = 0; i < 256; ++i) s += cat0[i] * w1[i * 256 + t];
        h0[t] = fmaxf(s, 0.0f);
    }
    __syncthreads();
    if (t < 128) {
        float y = b2[t];
        for (int j = 0; j < 256; ++j) y += h0[j] * w2[j * 128 + t];
        x0n[t] = x0[t] + y;
    }
}

// ---------- combine x1 = (x_v_new + sum yp)/(1+suffix); LN -> cat2 ----------
__global__ __launch_bounds__(256) void k_combine(const float* __restrict__ xnewV, const float* __restrict__ yp,
                                                 const float* __restrict__ suffix, const float* __restrict__ pe2,
                                                 const float* __restrict__ g, const float* __restrict__ bn,
                                                 float* __restrict__ x1, u16* __restrict__ cat2) {
    int wave = threadIdx.x >> 6, lane = threadIdx.x & 63;
    int row = blockIdx.x * 4 + wave;
    int c = lane * 2;
    float2 v = *(const float2*)(xnewV + (size_t)row * DD + c);
#pragma unroll
    for (int s = 0; s < 4; ++s) {
        float2 y = *(const float2*)(yp + ((size_t)s * NV + row) * DD + c);
        v.x += y.x; v.y += y.y;
    }
    float inv = 1.0f / (1.0f + suffix[row]);
    v.x *= inv; v.y *= inv;
    *(float2*)(x1 + (size_t)row * DD + c) = v;
    float mu = wsum(v.x + v.y) * (1.0f / DD);
    float var = wsum(v.x * v.x + v.y * v.y) * (1.0f / DD) - mu * mu;
    float rstd = rsqrtf(var + 1e-5f);
    u16* crow = cat2 + (size_t)row * 256;
    crow[c]     = f2bf((v.x - mu) * rstd * g[c]     + bn[c]);
    crow[c + 1] = f2bf((v.y - mu) * rstd * g[c + 1] + bn[c + 1]);
    const float* pr = pe2 + DD;  // pe2 row 1
    crow[DD + c]     = f2bf(pr[c]);
    crow[DD + c + 1] = f2bf(pr[c + 1]);
}

// ---------- LN3: a3 = bf16(LN(xmid)*g+b) ----------
__global__ __launch_bounds__(256) void k_ln3(const float* __restrict__ xmid, const float* __restrict__ g,
                                             const float* __restrict__ bn, u16* __restrict__ a3) {
    int wave = threadIdx.x >> 6, lane = threadIdx.x & 63;
    int row = blockIdx.x * 4 + wave;
    int c = lane * 2;
    float2 v = *(const float2*)(xmid + (size_t)row * DD + c);
    float mu = wsum(v.x + v.y) * (1.0f / DD);
    float var = wsum(v.x * v.x + v.y * v.y) * (1.0f / DD) - mu * mu;
    float rstd = rsqrtf(var + 1e-5f);
    a3[(size_t)row * DD + c]     = f2bf((v.x - mu) * rstd * g[c]     + bn[c]);
    a3[(size_t)row * DD + c + 1] = f2bf((v.y - mu) * rstd * g[c + 1] + bn[c + 1]);
}

// ==================== launch ====================
extern "C" void kernel_launch(void* const* d_in, const int* in_sizes, int n_in,
                              void* d_out, int out_size, void* d_ws, size_t ws_size,
                              hipStream_t stream) {
    const float* x_v    = (const float*)d_in[0];
    const float* x_e    = (const float*)d_in[1];
    const float* inc    = (const float*)d_in[2];
    const float* suffix = (const float*)d_in[3];
    const int*   orders = (const int*)d_in[4];
    const float* m1w1 = (const float*)d_in[5];
    const float* m1b1 = (const float*)d_in[6];
    const float* m1w2 = (const float*)d_in[7];
    const float* m1b2 = (const float*)d_in[8];
    const float* m2w1 = (const float*)d_in[9];
    const float* m2b1 = (const float*)d_in[10];
    const float* m2w2 = (const float*)d_in[11];
    const float* m2b2 = (const float*)d_in[12];
    const float* m3w1 = (const float*)d_in[13];
    const float* m3b1 = (const float*)d_in[14];
    const float* m3w2 = (const float*)d_in[15];
    const float* m3b2 = (const float*)d_in[16];
    const float* g1 = (const float*)d_in[17];
    const float* b1n = (const float*)d_in[18];
    const float* g2 = (const float*)d_in[19];
    const float* b2n = (const float*)d_in[20];
    const float* g3 = (const float*)d_in[21];
    const float* b3n = (const float*)d_in[22];
    const float* bb = (const float*)d_in[23];
    float* out = (float*)d_out;

    char* w = (char*)d_ws;
    float* pe1   = (float*)(w + 0);
    float* pe2   = (float*)(w + 4608);
    float* x0n   = (float*)(w + 5632);
    u16* w11t    = (u16*)(w + 8192);
    u16* w12t    = (u16*)(w + 139264);
    u16* w21t    = (u16*)(w + 204800);
    u16* w22t    = (u16*)(w + 335872);
    u16* w31t    = (u16*)(w + 401408);
    u16* w32t    = (u16*)(w + 466944);
    float* part  = (float*)(w + 532480);
    u16* cat1    = (u16*)(w + 1048576);
    u16* h1      = (u16*)(w + 13631488);
    float* xnew  = (float*)(w + 26214400);
    u16* xeT     = (u16*)(w + 38797312);
    float* yp    = (float*)(w + 42991616);
    float* x1    = (float*)(w + 59768832);
    u16* cat2    = (u16*)(w + 63963136);
    u16* h2      = (u16*)(w + 68157440);
    float* xmid  = (float*)(w + 72351744);
    u16* a3      = (u16*)(w + 76546048);
    u16* h3      = (u16*)(w + 78643200);

    k_pe<<<1, 256, 0, stream>>>(pe1, pe2);
    k_twcvt<<<256, 256, 0, stream>>>(m1w1, w11t, 256, 256);
    k_twcvt<<<128, 256, 0, stream>>>(m1w2, w12t, 256, 128);
    k_twcvt<<<256, 256, 0, stream>>>(m2w1, w21t, 256, 256);
    k_twcvt<<<128, 256, 0, stream>>>(m2w2, w22t, 256, 128);
    k_twcvt<<<128, 256, 0, stream>>>(m3w1, w31t, 128, 256);
    k_twcvt<<<128, 256, 0, stream>>>(m3w2, w32t, 256, 128);

    k_ln_cat1<<<MTOT / 4, 256, 0, stream>>>(x_v, x_e, orders, pe1, g1, b1n, cat1);
    k_fc_relu<256, 256><<<MTOT / 64, 256, 0, stream>>>(cat1, w11t, m1b1, h1);
    k_fc2_s1<<<MTOT / 64, 256, 0, stream>>>(h1, w12t, m1b2, x_v, x_e, xnew, xeT);

    k_colsum<<<MTOT / 128, 256, 0, stream>>>(xnew, part);
    k_x0<<<1, 256, 0, stream>>>(part, pe2, m2w1, m2b1, m2w2, m2b2, g2, b2n, x0n);

    k_big<<<dim3(NV / 64, 4), 256, 0, stream>>>(inc, xeT, yp);

    k_combine<<<NV / 4, 256, 0, stream>>>(xnew, yp, suffix, pe2, g2, b2n, x1, cat2);
    k_fc_relu<256, 256><<<NV / 64, 256, 0, stream>>>(cat2, w21t, m2b1, h2);
    k_fc2_s2<<<NV / 64, 256, 0, stream>>>(h2, w22t, m2b2, x1, x0n, xmid);

    k_ln3<<<NV / 4, 256, 0, stream>>>(xmid, g3, b3n, a3);
    k_fc_relu<128, 256><<<NV / 64, 256, 0, stream>>>(a3, w31t, m3b1, h3);
    k_fc2_s3<<<NV / 64, 256, 0, stream>>>(h3, w32t, m3b2, xmid, bb, out);
}

// Round 2
// 306.631 us; speedup vs baseline: 1.7690x; 1.7690x over previous
//
#include <hip/hip_runtime.h>

typedef __attribute__((ext_vector_type(4))) float f32x4;
typedef __attribute__((ext_vector_type(8))) short s16x8;
typedef unsigned short u16;

#define NV 8192
#define NE 16384
#define MTOT 24576
#define DD 128
#define HH 256

#define BIGSPLIT 8
#define BKS 64
#define KRANGE (NE / BIGSPLIT)   // 2048
#define NSTEPB (KRANGE / BKS)    // 32

// ---------- helpers ----------
__device__ __forceinline__ u16 f2bf(float f) {
    unsigned u = __builtin_bit_cast(unsigned, f);
    u += 0x7fffu + ((u >> 16) & 1u);   // RTNE
    return (u16)(u >> 16);
}

__device__ __forceinline__ float wsum(float v) {
#pragma unroll
    for (int o = 32; o > 0; o >>= 1) v += __shfl_xor(v, o, 64);
    return v;
}

__device__ __forceinline__ f32x4 ntload4(const float* p) {
    return __builtin_nontemporal_load((const f32x4*)p);
}

// ---------- PE tables ----------
__global__ void k_pe(float* __restrict__ pe1, float* __restrict__ pe2) {
    const float c = logf(10000.0f) / 64.0f;
    for (int idx = threadIdx.x; idx < 9 * DD; idx += 256) {
        int p = idx / DD, col = idx % DD, j = col >> 1;
        float a = (float)p * expf(-(float)j * c);
        pe1[idx] = (col & 1) ? cosf(a) : sinf(a);
    }
    for (int idx = threadIdx.x; idx < 2 * DD; idx += 256) {
        int p = idx / DD, col = idx % DD, j = col >> 1;
        float a = (float)p * expf(-(float)j * c);
        pe2[idx] = (col & 1) ? cosf(a) : sinf(a);
    }
}

// ---------- pack weights into MFMA-fragment order ----------
// src fp32 [K][C]; element (k,n) -> dst[(((k>>5)*(C/16)+(n>>4))*64 + (n&15) + (((k&31)>>3)<<4))*8 + (k&7)]
__global__ void k_wpack(const float* __restrict__ src, u16* __restrict__ dst, int K, int C) {
    int i = blockIdx.x * 256 + threadIdx.x;
    if (i < K * C) {
        int k = i / C, n = i % C;
        size_t o = (((size_t)(k >> 5) * (C >> 4) + (n >> 4)) * 64 + (n & 15) + (((k & 31) >> 3) << 4)) * 8 + (k & 7);
        dst[o] = f2bf(src[i]);
    }
}

// ---------- LN + concat(PE) stage 1 ----------
__global__ __launch_bounds__(256) void k_ln_cat1(const float* __restrict__ xv, const float* __restrict__ xe,
                                                 const int* __restrict__ orders, const float* __restrict__ pe1,
                                                 const float* __restrict__ g, const float* __restrict__ bn,
                                                 u16* __restrict__ cat) {
    int wave = threadIdx.x >> 6, lane = threadIdx.x & 63;
    int row = blockIdx.x * 4 + wave;
    const float* x = (row < NV) ? xv + (size_t)row * DD : xe + (size_t)(row - NV) * DD;
    float2 v = *(const float2*)(x + lane * 2);
    float mu = wsum(v.x + v.y) * (1.0f / DD);
    float var = wsum(v.x * v.x + v.y * v.y) * (1.0f / DD) - mu * mu;
    float rs = rsqrtf(var + 1e-5f);
    int c = lane * 2;
    u16* crow = cat + (size_t)row * 256;
    crow[c]     = f2bf((v.x - mu) * rs * g[c]     + bn[c]);
    crow[c + 1] = f2bf((v.y - mu) * rs * g[c + 1] + bn[c + 1]);
    const float* pr = pe1 + (size_t)((row < NV) ? 1 : orders[row - NV]) * DD;
    crow[DD + c]     = f2bf(pr[c]);
    crow[DD + c + 1] = f2bf(pr[c + 1]);
}

// ---------- MFMA core with packed B: 4 waves, each owns 16 rows ----------
template <int K, int NN>
__device__ __forceinline__ void fc_core(const u16* __restrict__ A, const u16* __restrict__ Bp,
                                        int rowb, int lane, f32x4* acc) {
    const u16* ap = A + (size_t)(rowb + (lane & 15)) * K + ((lane >> 4) << 3);
    const s16x8* bp = (const s16x8*)Bp + lane;
#pragma unroll
    for (int ks = 0; ks < K / 32; ++ks) {
        s16x8 a = *(const s16x8*)(ap + ks * 32);
#pragma unroll
        for (int nt = 0; nt < NN / 16; ++nt) {
            s16x8 b = bp[(size_t)(ks * (NN / 16) + nt) * 64];
            acc[nt] = __builtin_amdgcn_mfma_f32_16x16x32_bf16(a, b, acc[nt], 0, 0, 0);
        }
    }
}

// ---------- fc1: out = relu(A@W + b) bf16 ----------
template <int K, int NN>
__global__ __launch_bounds__(256) void k_fc_relu(const u16* __restrict__ A, const u16* __restrict__ Bp,
                                                 const float* __restrict__ bias, u16* __restrict__ out) {
    int lane = threadIdx.x & 63, wave = threadIdx.x >> 6;
    int rowb = blockIdx.x * 64 + wave * 16;
    f32x4 acc[NN / 16];
#pragma unroll
    for (int nt = 0; nt < NN / 16; ++nt)
#pragma unroll
        for (int j = 0; j < 4; ++j) acc[nt][j] = 0.0f;
    fc_core<K, NN>(A, Bp, rowb, lane, acc);
#pragma unroll
    for (int nt = 0; nt < NN / 16; ++nt)
#pragma unroll
        for (int j = 0; j < 4; ++j) {
            int r = rowb + ((lane >> 4) << 2) + j;
            int c = nt * 16 + (lane & 15);
            out[(size_t)r * NN + c] = f2bf(fmaxf(acc[nt][j] + bias[c], 0.0f));
        }
}

// ---------- fc2 stage1: xnew = residual + A@W + b; edge rows also -> packed B for big GEMM ----------
__global__ __launch_bounds__(256) void k_fc2_s1(const u16* __restrict__ A, const u16* __restrict__ Bp,
                                                const float* __restrict__ bias, const float* __restrict__ xv,
                                                const float* __restrict__ xe, float* __restrict__ xnew,
                                                u16* __restrict__ bpack) {
    int lane = threadIdx.x & 63, wave = threadIdx.x >> 6;
    int rowb = blockIdx.x * 64 + wave * 16;
    f32x4 acc[8];
#pragma unroll
    for (int nt = 0; nt < 8; ++nt)
#pragma unroll
        for (int j = 0; j < 4; ++j) acc[nt][j] = 0.0f;
    fc_core<256, 128>(A, Bp, rowb, lane, acc);
    int r0 = rowb + ((lane >> 4) << 2);
    int cb = lane & 15;
    bool isE = (r0 >= NV);
    int e0 = r0 - NV;
#pragma unroll
    for (int nt = 0; nt < 8; ++nt) {
        int c = nt * 16 + cb;
        float vv[4];
#pragma unroll
        for (int j = 0; j < 4; ++j) {
            int r = r0 + j;
            float res = isE ? xe[(size_t)(r - NV) * DD + c] : xv[(size_t)r * DD + c];
            vv[j] = acc[nt][j] + bias[c] + res;
            xnew[(size_t)r * DD + c] = vv[j];
        }
        if (isE) {
            ushort4 p;
            p.x = f2bf(vv[0]); p.y = f2bf(vv[1]); p.z = f2bf(vv[2]); p.w = f2bf(vv[3]);
            size_t o = (((size_t)(e0 >> 5) * 8 + nt) * 64 + cb + (((e0 & 31) >> 3) << 4)) * 8 + (e0 & 7);
            *(ushort4*)(bpack + o) = p;
        }
    }
}

// ---------- fc2 stage2: xmid = x1 + A@W + b + x0_new ----------
__global__ __launch_bounds__(256) void k_fc2_s2(const u16* __restrict__ A, const u16* __restrict__ Bp,
                                                const float* __restrict__ bias, const float* __restrict__ x1,
                                                const float* __restrict__ x0n, float* __restrict__ xmid) {
    int lane = threadIdx.x & 63, wave = threadIdx.x >> 6;
    int rowb = blockIdx.x * 64 + wave * 16;
    f32x4 acc[8];
#pragma unroll
    for (int nt = 0; nt < 8; ++nt)
#pragma unroll
        for (int j = 0; j < 4; ++j) acc[nt][j] = 0.0f;
    fc_core<256, 128>(A, Bp, rowb, lane, acc);
#pragma unroll
    for (int nt = 0; nt < 8; ++nt)
#pragma unroll
        for (int j = 0; j < 4; ++j) {
            int r = rowb + ((lane >> 4) << 2) + j;
            int c = nt * 16 + (lane & 15);
            xmid[(size_t)r * DD + c] = acc[nt][j] + bias[c] + x1[(size_t)r * DD + c] + x0n[c];
        }
}

// ---------- fc2 stage3: out = xmid + A@W + b + bias_b ----------
__global__ __launch_bounds__(256) void k_fc2_s3(const u16* __restrict__ A, const u16* __restrict__ Bp,
                                                const float* __restrict__ bias, const float* __restrict__ xmid,
                                                const float* __restrict__ bb, float* __restrict__ out) {
    int lane = threadIdx.x & 63, wave = threadIdx.x >> 6;
    int rowb = blockIdx.x * 64 + wave * 16;
    f32x4 acc[8];
#pragma unroll
    for (int nt = 0; nt < 8; ++nt)
#pragma unroll
        for (int j = 0; j < 4; ++j) acc[nt][j] = 0.0f;
    fc_core<256, 128>(A, Bp, rowb, lane, acc);
#pragma unroll
    for (int nt = 0; nt < 8; ++nt)
#pragma unroll
        for (int j = 0; j < 4; ++j) {
            int r = rowb + ((lane >> 4) << 2) + j;
            int c = nt * 16 + (lane & 15);
            out[(size_t)r * DD + c] = acc[nt][j] + bias[c] + xmid[(size_t)r * DD + c] + bb[c];
        }
}

// ---------- big GEMM: yp[split] = inc[:, chunk] @ xe_new[chunk, :]  tiled, LDS-staged ----------
__global__ __launch_bounds__(256) void k_big(const float* __restrict__ inc, const u16* __restrict__ bpack,
                                             float* __restrict__ yp) {
    __shared__ u16 aT[128 * 72];     // 18 KB, pitch 72 (pad breaks bank stride)
    __shared__ u16 bT[1024 * 8];     // 16 KB, fragment-packed
    int t = threadIdx.x;
    int lane = t & 63, w = t >> 6;
    int row0 = blockIdx.x * 128;
    int split = blockIdx.y;
    int kbase = split * KRANGE;

    const int sr = t >> 4;           // row within 16-row group per iter
    const int sc = (t & 15) * 4;     // col (floats)

    f32x4 ar[8];
    s16x8 br[4];

    f32x4 acc[2][8];
#pragma unroll
    for (int mt = 0; mt < 2; ++mt)
#pragma unroll
        for (int nt = 0; nt < 8; ++nt)
#pragma unroll
            for (int j = 0; j < 4; ++j) acc[mt][nt][j] = 0.0f;

    // prologue loads
    {
        int k0 = kbase;
#pragma unroll
        for (int i = 0; i < 8; ++i)
            ar[i] = ntload4(inc + (size_t)(row0 + i * 16 + sr) * NE + k0 + sc);
        const s16x8* src = (const s16x8*)bpack + (size_t)(k0 >> 5) * 512;
#pragma unroll
        for (int i = 0; i < 4; ++i) br[i] = src[i * 256 + t];
    }

    for (int step = 0; step < NSTEPB; ++step) {
        __syncthreads();   // previous compute done -> LDS writable
        // store staged regs to LDS
#pragma unroll
        for (int i = 0; i < 8; ++i) {
            ushort4 p;
            p.x = f2bf(ar[i][0]); p.y = f2bf(ar[i][1]); p.z = f2bf(ar[i][2]); p.w = f2bf(ar[i][3]);
            *(ushort4*)(aT + (size_t)(i * 16 + sr) * 72 + sc) = p;
        }
#pragma unroll
        for (int i = 0; i < 4; ++i)
            *(s16x8*)(bT + (size_t)(i * 256 + t) * 8) = br[i];
        __syncthreads();   // LDS ready

        // issue next-step global loads NOW (fly during MFMA phase)
        if (step + 1 < NSTEPB) {
            int k0 = kbase + (step + 1) * BKS;
#pragma unroll
            for (int i = 0; i < 8; ++i)
                ar[i] = ntload4(inc + (size_t)(row0 + i * 16 + sr) * NE + k0 + sc);
            const s16x8* src = (const s16x8*)bpack + (size_t)(k0 >> 5) * 512;
#pragma unroll
            for (int i = 0; i < 4; ++i) br[i] = src[i * 256 + t];
        }

        // compute: wave w owns rows w*32 .. w*32+31
        const u16* arow = aT + (size_t)(w * 32 + (lane & 15)) * 72 + ((lane >> 4) << 3);
#pragma unroll
        for (int kt = 0; kt < 2; ++kt) {
            s16x8 a0 = *(const s16x8*)(arow + kt * 32);
            s16x8 a1 = *(const s16x8*)(arow + 16 * 72 + kt * 32);
#pragma unroll
            for (int nt = 0; nt < 8; ++nt) {
                s16x8 b = *(const s16x8*)(bT + (size_t)((kt * 8 + nt) * 64 + lane) * 8);
                acc[0][nt] = __builtin_amdgcn_mfma_f32_16x16x32_bf16(a0, b, acc[0][nt], 0, 0, 0);
                acc[1][nt] = __builtin_amdgcn_mfma_f32_16x16x32_bf16(a1, b, acc[1][nt], 0, 0, 0);
            }
        }
    }

    int rb = row0 + w * 32 + ((lane >> 4) << 2);
    int cb = lane & 15;
#pragma unroll
    for (int mt = 0; mt < 2; ++mt)
#pragma unroll
        for (int nt = 0; nt < 8; ++nt)
#pragma unroll
            for (int j = 0; j < 4; ++j)
                yp[((size_t)split * NV + rb + mt * 16 + j) * DD + nt * 16 + cb] = acc[mt][nt][j];
}

// ---------- column-sum partials over xnew ----------
__global__ __launch_bounds__(256) void k_colsum(const float* __restrict__ xnew, float* __restrict__ part) {
    int t = threadIdx.x, col = t & 127, half = t >> 7;
    int r0 = blockIdx.x * 128;
    float s = 0.0f;
    for (int i = half; i < 128; i += 2) s += xnew[(size_t)(r0 + i) * DD + col];
    __shared__ float sh[256];
    sh[t] = s;
    __syncthreads();
    if (t < 128) part[blockIdx.x * 128 + t] = sh[t] + sh[t + 128];
}

// ---------- x0 path ----------
__global__ __launch_bounds__(256) void k_x0(const float* __restrict__ part, const float* __restrict__ pe2,
                                            const float* __restrict__ w1, const float* __restrict__ b1,
                                            const float* __restrict__ w2, const float* __restrict__ b2,
                                            const float* __restrict__ g, const float* __restrict__ bn,
                                            float* __restrict__ x0n) {
    __shared__ float x0[128], cat0[256], h0[256], rs_[128], rq_[128];
    int t = threadIdx.x;
    if (t < 128) {
        float s = 0.0f;
        for (int p = 0; p < 192; ++p) s += part[p * 128 + t];
        x0[t] = s * (1.0f / MTOT);
        rs_[t] = x0[t];
        rq_[t] = x0[t] * x0[t];
    }
    __syncthreads();
    for (int off = 64; off > 0; off >>= 1) {
        if (t < off) { rs_[t] += rs_[t + off]; rq_[t] += rq_[t + off]; }
        __syncthreads();
    }
    float mu = rs_[0] * (1.0f / DD);
    float var = rq_[0] * (1.0f / DD) - mu * mu;
    float rstd = rsqrtf(var + 1e-5f);
    if (t < 128) {
        cat0[t] = (x0[t] - mu) * rstd * g[t] + bn[t];
        cat0[128 + t] = pe2[t];
    }
    __syncthreads();
    {
        float s = b1[t];
        for (int i = 0; i < 256; ++i) s += cat0[i] * w1[i * 256 + t];
        h0[t] = fmaxf(s, 0.0f);
    }
    __syncthreads();
    if (t < 128) {
        float y = b2[t];
        for (int j = 0; j < 256; ++j) y += h0[j] * w2[j * 128 + t];
        x0n[t] = x0[t] + y;
    }
}

// ---------- combine: x1 = (x_v_new + sum yp)/(1+suffix); LN -> cat2 ----------
__global__ __launch_bounds__(256) void k_combine(const float* __restrict__ xnewV, const float* __restrict__ yp,
                                                 const float* __restrict__ suffix, const float* __restrict__ pe2,
                                                 const float* __restrict__ g, const float* __restrict__ bn,
                                                 float* __restrict__ x1, u16* __restrict__ cat2) {
    int wave = threadIdx.x >> 6, lane = threadIdx.x & 63;
    int row = blockIdx.x * 4 + wave;
    int c = lane * 2;
    float2 v = *(const float2*)(xnewV + (size_t)row * DD + c);
#pragma unroll
    for (int s = 0; s < BIGSPLIT; ++s) {
        float2 y = *(const float2*)(yp + ((size_t)s * NV + row) * DD + c);
        v.x += y.x; v.y += y.y;
    }
    float inv = 1.0f / (1.0f + suffix[row]);
    v.x *= inv; v.y *= inv;
    *(float2*)(x1 + (size_t)row * DD + c) = v;
    float mu = wsum(v.x + v.y) * (1.0f / DD);
    float var = wsum(v.x * v.x + v.y * v.y) * (1.0f / DD) - mu * mu;
    float rstd = rsqrtf(var + 1e-5f);
    u16* crow = cat2 + (size_t)row * 256;
    crow[c]     = f2bf((v.x - mu) * rstd * g[c]     + bn[c]);
    crow[c + 1] = f2bf((v.y - mu) * rstd * g[c + 1] + bn[c + 1]);
    const float* pr = pe2 + DD;
    crow[DD + c]     = f2bf(pr[c]);
    crow[DD + c + 1] = f2bf(pr[c + 1]);
}

// ---------- LN3 ----------
__global__ __launch_bounds__(256) void k_ln3(const float* __restrict__ xmid, const float* __restrict__ g,
                                             const float* __restrict__ bn, u16* __restrict__ a3) {
    int wave = threadIdx.x >> 6, lane = threadIdx.x & 63;
    int row = blockIdx.x * 4 + wave;
    int c = lane * 2;
    float2 v = *(const float2*)(xmid + (size_t)row * DD + c);
    float mu = wsum(v.x + v.y) * (1.0f / DD);
    float var = wsum(v.x * v.x + v.y * v.y) * (1.0f / DD) - mu * mu;
    float rstd = rsqrtf(var + 1e-5f);
    a3[(size_t)row * DD + c]     = f2bf((v.x - mu) * rstd * g[c]     + bn[c]);
    a3[(size_t)row * DD + c + 1] = f2bf((v.y - mu) * rstd * g[c + 1] + bn[c + 1]);
}

// ==================== launch ====================
extern "C" void kernel_launch(void* const* d_in, const int* in_sizes, int n_in,
                              void* d_out, int out_size, void* d_ws, size_t ws_size,
                              hipStream_t stream) {
    const float* x_v    = (const float*)d_in[0];
    const float* x_e    = (const float*)d_in[1];
    const float* inc    = (const float*)d_in[2];
    const float* suffix = (const float*)d_in[3];
    const int*   orders = (const int*)d_in[4];
    const float* m1w1 = (const float*)d_in[5];
    const float* m1b1 = (const float*)d_in[6];
    const float* m1w2 = (const float*)d_in[7];
    const float* m1b2 = (const float*)d_in[8];
    const float* m2w1 = (const float*)d_in[9];
    const float* m2b1 = (const float*)d_in[10];
    const float* m2w2 = (const float*)d_in[11];
    const float* m2b2 = (const float*)d_in[12];
    const float* m3w1 = (const float*)d_in[13];
    const float* m3b1 = (const float*)d_in[14];
    const float* m3w2 = (const float*)d_in[15];
    const float* m3b2 = (const float*)d_in[16];
    const float* g1 = (const float*)d_in[17];
    const float* b1n = (const float*)d_in[18];
    const float* g2 = (const float*)d_in[19];
    const float* b2n = (const float*)d_in[20];
    const float* g3 = (const float*)d_in[21];
    const float* b3n = (const float*)d_in[22];
    const float* bb = (const float*)d_in[23];
    float* out = (float*)d_out;

    char* w = (char*)d_ws;
    float* pe1   = (float*)(w + 0);
    float* pe2   = (float*)(w + 4608);
    float* x0n   = (float*)(w + 5632);
    float* part  = (float*)(w + 6144);
    u16* w11t    = (u16*)(w + 104448);
    u16* w12t    = (u16*)(w + 235520);
    u16* w21t    = (u16*)(w + 301056);
    u16* w22t    = (u16*)(w + 432128);
    u16* w31t    = (u16*)(w + 497664);
    u16* w32t    = (u16*)(w + 563200);
    // region1: cat1, later cat2 + xmid
    u16* cat1    = (u16*)(w + 1048576);
    u16* cat2    = (u16*)(w + 1048576);
    float* xmid  = (float*)(w + 1048576 + 4194304);
    // region2: h1, later h2 + a3 + h3
    u16* h1      = (u16*)(w + 13631488);
    u16* h2      = (u16*)(w + 13631488);
    u16* a3      = (u16*)(w + 13631488 + 4194304);
    u16* h3      = (u16*)(w + 13631488 + 6291456);
    float* xnew  = (float*)(w + 26214400);
    u16* bpack   = (u16*)(w + 38797312);
    float* yp    = (float*)(w + 42991616);
    float* x1    = (float*)(w + 76546048);
    // end: 80740352 bytes

    k_pe<<<1, 256, 0, stream>>>(pe1, pe2);
    k_wpack<<<256, 256, 0, stream>>>(m1w1, w11t, 256, 256);
    k_wpack<<<128, 256, 0, stream>>>(m1w2, w12t, 256, 128);
    k_wpack<<<256, 256, 0, stream>>>(m2w1, w21t, 256, 256);
    k_wpack<<<128, 256, 0, stream>>>(m2w2, w22t, 256, 128);
    k_wpack<<<128, 256, 0, stream>>>(m3w1, w31t, 128, 256);
    k_wpack<<<128, 256, 0, stream>>>(m3w2, w32t, 256, 128);

    k_ln_cat1<<<MTOT / 4, 256, 0, stream>>>(x_v, x_e, orders, pe1, g1, b1n, cat1);
    k_fc_relu<256, 256><<<MTOT / 64, 256, 0, stream>>>(cat1, w11t, m1b1, h1);
    k_fc2_s1<<<MTOT / 64, 256, 0, stream>>>(h1, w12t, m1b2, x_v, x_e, xnew, bpack);

    k_colsum<<<MTOT / 128, 256, 0, stream>>>(xnew, part);
    k_x0<<<1, 256, 0, stream>>>(part, pe2, m2w1, m2b1, m2w2, m2b2, g2, b2n, x0n);

    k_big<<<dim3(NV / 128, BIGSPLIT), 256, 0, stream>>>(inc, bpack, yp);

    k_combine<<<NV / 4, 256, 0, stream>>>(xnew, yp, suffix, pe2, g2, b2n, x1, cat2);
    k_fc_relu<256, 256><<<NV / 64, 256, 0, stream>>>(cat2, w21t, m2b1, h2);
    k_fc2_s2<<<NV / 64, 256, 0, stream>>>(h2, w22t, m2b2, x1, x0n, xmid);

    k_ln3<<<NV / 4, 256, 0, stream>>>(xmid, g3, b3n, a3);
    k_fc_relu<128, 256><<<NV / 64, 256, 0, stream>>>(a3, w31t, m3b1, h3);
    k_fc2_s3<<<NV / 64, 256, 0, stream>>>(h3, w32t, m3b2, xmid, bb, out);
}